// Round 19
// baseline (192.811 us; speedup 1.0000x reference)
//
#include <hip/hip_runtime.h>
#include <stdint.h>

// LocalAttention: x[2,2048,1024] -> QKV proj -> anti-local attention (keep |i-j|>16) -> out proj.
// Round 19: attn was LDS-pipe-bound (~88% busy: 28 b128 + 16 b64 per wave-iter). K and V now
// read DIRECTLY from global (L2-local via XCD remap; 4x amplification = ~7us of L2 BW) with
// one-tile-ahead prefetch into NAMED bf16x8 registers (rule #20). LDS carries only the P tile;
// all barriers removed (waves free-run). GEMMs/f2b5 unchanged from round 18.

typedef unsigned short u16;
typedef short bf16x8 __attribute__((ext_vector_type(8)));
typedef float f32x4 __attribute__((ext_vector_type(4)));

#define MFMA16 __builtin_amdgcn_mfma_f32_16x16x32_bf16

__device__ __forceinline__ u16 f2bf(float f) {
  union { float f; uint32_t u; } v; v.f = f;
  return (u16)((v.u + 0x7fffu + ((v.u >> 16) & 1u)) >> 16);
}

__device__ __forceinline__ uint32_t cvt_pk_bf16(float lo, float hi) {
  uint32_t d;
  asm("v_cvt_pk_bf16_f32 %0, %1, %2" : "=v"(d) : "v"(lo), "v"(hi));
  return d;
}

// raw hardware exp2 (v_exp_f32 IS exp2 on gfx950; no libm guard code)
__device__ __forceinline__ float hexp2(float x) {
  float r;
  asm("v_exp_f32 %0, %1" : "=v"(r) : "v"(x));
  return r;
}

// ---------------- fp32 -> bf16 conversion (x + 4 weights, ONE launch) ----------------
__global__ void f2b5_kernel(const float* __restrict__ x,
                            const float* __restrict__ a, const float* __restrict__ b,
                            const float* __restrict__ c, const float* __restrict__ d,
                            u16* __restrict__ ox, u16* __restrict__ oa, u16* __restrict__ ob,
                            u16* __restrict__ oc, u16* __restrict__ od) {
  int bid = blockIdx.x;
  const float* src; u16* dst; int base;
  if (bid < 4096)      { src = x; dst = ox; base = 0; }
  else if (bid < 5120) { src = a; dst = oa; base = 4096; }
  else if (bid < 6144) { src = b; dst = ob; base = 5120; }
  else if (bid < 7168) { src = c; dst = oc; base = 6144; }
  else                 { src = d; dst = od; base = 7168; }
  int i = (bid - base) * 256 + threadIdx.x;
  float4 v = reinterpret_cast<const float4*>(src)[i];
  ushort4 o;
  o.x = f2bf(v.x); o.y = f2bf(v.y); o.z = f2bf(v.z); o.w = f2bf(v.w);
  reinterpret_cast<ushort4*>(dst)[i] = o;
}

// ---------------- shared GEMM core (padded LDS, reg-staged, NAMED registers) ----------------
#define GEMM_LOAD(REGA, REGB, A_, B_, KOFF)                                                        \
  do {                                                                                             \
    REGA##0 = *reinterpret_cast<const uint4*>(A_ + (size_t)(gm_base +  0) * 1024 + (KOFF) + sslot * 8); \
    REGA##1 = *reinterpret_cast<const uint4*>(A_ + (size_t)(gm_base + 32) * 1024 + (KOFF) + sslot * 8); \
    REGA##2 = *reinterpret_cast<const uint4*>(A_ + (size_t)(gm_base + 64) * 1024 + (KOFF) + sslot * 8); \
    REGA##3 = *reinterpret_cast<const uint4*>(A_ + (size_t)(gm_base + 96) * 1024 + (KOFF) + sslot * 8); \
    REGB##0 = *reinterpret_cast<const uint4*>(B_ + (size_t)(gn_base +  0) * 1024 + (KOFF) + sslot * 8); \
    REGB##1 = *reinterpret_cast<const uint4*>(B_ + (size_t)(gn_base + 32) * 1024 + (KOFF) + sslot * 8); \
    REGB##2 = *reinterpret_cast<const uint4*>(B_ + (size_t)(gn_base + 64) * 1024 + (KOFF) + sslot * 8); \
    REGB##3 = *reinterpret_cast<const uint4*>(B_ + (size_t)(gn_base + 96) * 1024 + (KOFF) + sslot * 8); \
  } while (0)

#define GEMM_PUBLISH()                                                                             \
  do {                                                                                             \
    *reinterpret_cast<uint4*>((char*)As + (srow +  0) * 144 + sslot * 16) = ar0;                   \
    *reinterpret_cast<uint4*>((char*)As + (srow + 32) * 144 + sslot * 16) = ar1;                   \
    *reinterpret_cast<uint4*>((char*)As + (srow + 64) * 144 + sslot * 16) = ar2;                   \
    *reinterpret_cast<uint4*>((char*)As + (srow + 96) * 144 + sslot * 16) = ar3;                   \
    *reinterpret_cast<uint4*>((char*)Bs + (srow +  0) * 144 + sslot * 16) = br0;                   \
    *reinterpret_cast<uint4*>((char*)Bs + (srow + 32) * 144 + sslot * 16) = br1;                   \
    *reinterpret_cast<uint4*>((char*)Bs + (srow + 64) * 144 + sslot * 16) = br2;                   \
    *reinterpret_cast<uint4*>((char*)Bs + (srow + 96) * 144 + sslot * 16) = br3;                   \
  } while (0)

#define GEMM_CORE(A_, B_, bm0_, bn0_)                                                              \
  constexpr int KP = 72;                                                                           \
  __shared__ __align__(16) u16 As[128 * KP];                                                       \
  __shared__ __align__(16) u16 Bs[128 * KP];                                                       \
  const int t = threadIdx.x;                                                                       \
  const int lane = t & 63;                                                                         \
  const int wv = t >> 6;                                                                           \
  const int wm = (wv >> 1) * 64;                                                                   \
  const int wn = (wv & 1) * 64;                                                                    \
  const int lg = lane >> 4;                                                                        \
  const int lr = lane & 15;                                                                        \
  const int srow = t >> 3;                                                                         \
  const int sslot = t & 7;                                                                         \
  const int gm_base = bm0_ + srow;                                                                 \
  const int gn_base = bn0_ + srow;                                                                 \
  uint4 ar0, ar1, ar2, ar3, br0, br1, br2, br3;                                                    \
  f32x4 acc[4][4];                                                                                 \
  for (int i = 0; i < 4; ++i)                                                                      \
    for (int j = 0; j < 4; ++j) acc[i][j] = (f32x4)0.0f;                                           \
  GEMM_LOAD(ar, br, A_, B_, 0);                                                                    \
  for (int k0 = 0; k0 < 1024; k0 += 64) {                                                          \
    GEMM_PUBLISH();                                                                                \
    __syncthreads();                                                                               \
    if (k0 + 64 < 1024) GEMM_LOAD(ar, br, A_, B_, k0 + 64);                                        \
    for (int kk = 0; kk < 2; ++kk) {                                                               \
      bf16x8 af[4], bfr[4];                                                                        \
      for (int i = 0; i < 4; ++i)                                                                  \
        af[i] = *reinterpret_cast<const bf16x8*>(&As[(wm + i * 16 + lr) * KP + kk * 32 + lg * 8]); \
      for (int j = 0; j < 4; ++j)                                                                  \
        bfr[j] = *reinterpret_cast<const bf16x8*>(&Bs[(wn + j * 16 + lr) * KP + kk * 32 + lg * 8]);\
      for (int i = 0; i < 4; ++i)                                                                  \
        for (int j = 0; j < 4; ++j)                                                                \
          acc[i][j] = MFMA16(af[i], bfr[j], acc[i][j], 0, 0, 0);                                   \
    }                                                                                              \
    __syncthreads();                                                                               \
  }

// ---------------- fused QKV GEMM ----------------
__global__ __launch_bounds__(256) void gemm_qkv(
    const u16* __restrict__ A,
    const u16* __restrict__ Wqb, const u16* __restrict__ Wkb, const u16* __restrict__ Wvb,
    const float* __restrict__ bqp, const float* __restrict__ bkp, const float* __restrict__ bvp,
    u16* __restrict__ qo, u16* __restrict__ ko, u16* __restrict__ vo)
{
  const int bid = blockIdx.x + gridDim.x * blockIdx.y;
  const int sid = (bid & 7) * 96 + (bid >> 3);
  const int bm0 = (sid / 24) * 128;
  const int jy = sid % 24;
  const int sel = jy >> 3;
  const int bn0 = (jy & 7) * 128;

  const u16* Bw = (sel == 0) ? Wqb : (sel == 1) ? Wkb : Wvb;
  const float* bias = (sel == 0) ? bqp : (sel == 1) ? bkp : bvp;
  // Q scale folds softmax 1/8 AND log2(e) (exp2-domain softmax downstream)
  const float scale = (sel == 0) ? 0.125f * 1.44269504f : 1.0f;

  GEMM_CORE(A, Bw, bm0, bn0)

  for (int j = 0; j < 4; ++j) {
    int gn = bn0 + wn + j * 16 + lr;
    float bv = bias[gn];
    for (int i = 0; i < 4; ++i) {
      for (int r = 0; r < 4; ++r) {
        int gm = bm0 + wm + i * 16 + lg * 4 + r;
        float val = (acc[i][j][r] + bv) * scale;
        int b = gm >> 11, tt = gm & 2047;
        int h = gn >> 6,  d = gn & 63;
        u16 o = f2bf(val);
        if (sel == 0)
          qo[((size_t)(b * 16 + h) * 2048 + tt) * 64 + d] = o;
        else if (sel == 1)
          ko[((size_t)(b * 16 + h) * 2048 + tt) * 64 + d] = o;
        else
          vo[((size_t)(b * 16 + h) * 64 + d) * 2048 + tt] = o;
      }
    }
  }
}

// ---------------- out-proj GEMM: C[M,N] fp32 = A @ W^T + bias ----------------
__global__ __launch_bounds__(256) void gemm_out(
    const u16* __restrict__ A, const u16* __restrict__ Bw,
    const float* __restrict__ bias, float* __restrict__ outp)
{
  const int bm0 = blockIdx.x * 128;
  const int bn0 = blockIdx.y * 128;

  GEMM_CORE(A, Bw, bm0, bn0)

  for (int j = 0; j < 4; ++j) {
    int gn = bn0 + wn + j * 16 + lr;
    float bv = bias[gn];
    for (int i = 0; i < 4; ++i)
      for (int r = 0; r < 4; ++r) {
        int gm = bm0 + wm + i * 16 + lg * 4 + r;
        outp[(size_t)gm * 1024 + gn] = acc[i][j][r] + bv;
      }
  }
}

// ---------------- attention (direct-global K/V in named regs, P-only LDS, no barriers) ----------------
// grid 512 blocks remapped XCD-aware (4 heads/XCD -> K/V L2-resident). Block: 4 waves,
// 128 q-rows; wave owns 32 q-rows (qi=2). K frag kXn: rows kc*16+lr, cols h*32+lg*8 from
// [B,H,T,D]; V frag vXn: row d*16+lr, keys kh*32+lg*8 from [B,H,D,T] - both per-lane direct.
// Prefetch tile t+1 into the SAME named regs right after tile t's use (WAR-safe, in-order issue).
__global__ __launch_bounds__(256) void attn_kernel(
    const u16* __restrict__ qb, const u16* __restrict__ kb,
    const u16* __restrict__ vtb, u16* __restrict__ ab)
{
  __shared__ __align__(16) u16 Pl[4][32 * 64];

  const int bid = blockIdx.x + gridDim.x * blockIdx.y;
  const int sid = (bid & 7) * 64 + (bid >> 3);
  const int bx = sid & 15;
  const int bh = sid >> 4;                   // b*16+h

  const int t = threadIdx.x;
  const int lane = t & 63;
  const int wv = t >> 6;
  const int lg = lane >> 4, lr = lane & 15;
  const int q0 = bx * 128 + wv * 32;

  const u16* Qp = qb + (size_t)bh * 2048 * 64;
  const u16* Kp = kb + (size_t)bh * 2048 * 64 + (size_t)lr * 64 + lg * 8;    // +(j0+kc*16)*64 + h*32
  const u16* Vt = vtb + (size_t)bh * 64 * 2048 + (size_t)lr * 2048 + lg * 8; // + d*32768 + j0 + kh*32
  char* Pw = (char*)&Pl[wv][0];
  const int swz = (lr & 7) << 4;             // P-tile XOR swizzle (proven)

  // named K/V fragment registers (rule #20: arrays would spill)
  bf16x8 kA0, kB0, kA1, kB1, kA2, kB2, kA3, kB3;   // A=cols 0-31, B=cols 32-63; digit=kc
  bf16x8 vA0, vB0, vA1, vB1, vA2, vB2, vA3, vB3;   // A=keys lo 32, B=keys hi 32; digit=d

#define LOAD_K(J0)                                                                        \
  do {                                                                                    \
    kA0 = *reinterpret_cast<const bf16x8*>(Kp + (size_t)((J0) +  0) * 64 +  0);           \
    kB0 = *reinterpret_cast<const bf16x8*>(Kp + (size_t)((J0) +  0) * 64 + 32);           \
    kA1 = *reinterpret_cast<const bf16x8*>(Kp + (size_t)((J0) + 16) * 64 +  0);           \
    kB1 = *reinterpret_cast<const bf16x8*>(Kp + (size_t)((J0) + 16) * 64 + 32);           \
    kA2 = *reinterpret_cast<const bf16x8*>(Kp + (size_t)((J0) + 32) * 64 +  0);           \
    kB2 = *reinterpret_cast<const bf16x8*>(Kp + (size_t)((J0) + 32) * 64 + 32);           \
    kA3 = *reinterpret_cast<const bf16x8*>(Kp + (size_t)((J0) + 48) * 64 +  0);           \
    kB3 = *reinterpret_cast<const bf16x8*>(Kp + (size_t)((J0) + 48) * 64 + 32);           \
  } while (0)

#define LOAD_V(J0)                                                                        \
  do {                                                                                    \
    vA0 = *reinterpret_cast<const bf16x8*>(Vt + (size_t)0 * 32768 + (J0) +  0);           \
    vB0 = *reinterpret_cast<const bf16x8*>(Vt + (size_t)0 * 32768 + (J0) + 32);           \
    vA1 = *reinterpret_cast<const bf16x8*>(Vt + (size_t)1 * 32768 + (J0) +  0);           \
    vB1 = *reinterpret_cast<const bf16x8*>(Vt + (size_t)1 * 32768 + (J0) + 32);           \
    vA2 = *reinterpret_cast<const bf16x8*>(Vt + (size_t)2 * 32768 + (J0) +  0);           \
    vB2 = *reinterpret_cast<const bf16x8*>(Vt + (size_t)2 * 32768 + (J0) + 32);           \
    vA3 = *reinterpret_cast<const bf16x8*>(Vt + (size_t)3 * 32768 + (J0) +  0);           \
    vB3 = *reinterpret_cast<const bf16x8*>(Vt + (size_t)3 * 32768 + (J0) + 32);           \
  } while (0)

  bf16x8 qf[2][2];
  for (int qi = 0; qi < 2; ++qi)
    for (int h = 0; h < 2; ++h)
      qf[qi][h] = *reinterpret_cast<const bf16x8*>(&Qp[(size_t)(q0 + qi * 16 + lr) * 64 + h * 32 + lg * 8]);

  f32x4 o[2][4];
  for (int qi = 0; qi < 2; ++qi)
    for (int d = 0; d < 4; ++d) o[qi][d] = (f32x4)0.0f;
  float m[2] = {-1e30f, -1e30f};             // running max (log2 domain)
  float lsum[2] = {0.0f, 0.0f};              // per-lane partial sums (reduced in epilogue)

  LOAD_K(0);
  LOAD_V(0);

  for (int tt = 0; tt < 32; ++tt) {
    const int j0 = tt * 64;

    // ---- QK^T (swapped): s[qi][kc] -> lane: q=q0+qi*16+lr, key=j0+kc*16+lg*4+r
    f32x4 s[2][4];
    __builtin_amdgcn_s_setprio(1);
    {
      f32x4 z;
#define QK_KC(KC, KA, KB)                                                                 \
      z = (f32x4)0.0f; z = MFMA16(KA, qf[0][0], z, 0, 0, 0);                              \
      z = MFMA16(KB, qf[0][1], z, 0, 0, 0); s[0][KC] = z;                                 \
      z = (f32x4)0.0f; z = MFMA16(KA, qf[1][0], z, 0, 0, 0);                              \
      z = MFMA16(KB, qf[1][1], z, 0, 0, 0); s[1][KC] = z;
      QK_KC(0, kA0, kB0)
      QK_KC(1, kA1, kB1)
      QK_KC(2, kA2, kB2)
      QK_KC(3, kA3, kB3)
#undef QK_KC
    }
    __builtin_amdgcn_s_setprio(0);
    if (tt < 31) LOAD_K(j0 + 64);            // prefetch next K tile (WAR-safe: MFMAs issued)
    // ---- mask band |i-j| <= 16
    if (j0 + 63 >= q0 - 16 && j0 <= q0 + 47) {
      for (int qi = 0; qi < 2; ++qi)
        for (int kc = 0; kc < 4; ++kc)
          for (int r = 0; r < 4; ++r) {
            int i = q0 + qi * 16 + lr;
            int j = j0 + kc * 16 + lg * 4 + r;
            int dd = i - j; if (dd < 0) dd = -dd;
            if (dd <= 16) s[qi][kc][r] = -1e38f;
          }
    }
    // ---- tile row-max
    float pm[2];
    for (int qi = 0; qi < 2; ++qi) {
      f32x4 t4 = __builtin_elementwise_max(__builtin_elementwise_max(s[qi][0], s[qi][1]),
                                           __builtin_elementwise_max(s[qi][2], s[qi][3]));
      float x = fmaxf(fmaxf(t4[0], t4[1]), fmaxf(t4[2], t4[3]));
      x = fmaxf(x, __shfl_xor(x, 16));
      x = fmaxf(x, __shfl_xor(x, 32));
      pm[qi] = x;
    }
    // ---- defer-max rescale (log2 units; exp2(11.54) == exp(8) bound)
    bool need = (pm[0] > m[0] + 11.54f) || (pm[1] > m[1] + 11.54f);
    if (__any((int)need)) {
      for (int qi = 0; qi < 2; ++qi) {
        float mn = fmaxf(m[qi], pm[qi]);
        float a = hexp2(m[qi] - mn);
        m[qi] = mn;
        lsum[qi] *= a;
        for (int d = 0; d < 4; ++d) o[qi][d] *= a;
      }
    }
    // ---- p = exp2(s-m), pack to LDS; per-lane partial sum only (no shuffles)
    for (int qi = 0; qi < 2; ++qi) {
      int rowbase = (qi * 16 + lr) * 128;
      float psum = 0.0f;
      for (int kc = 0; kc < 4; ++kc) {
        float p0 = hexp2(s[qi][kc][0] - m[qi]);
        float p1 = hexp2(s[qi][kc][1] - m[qi]);
        float p2 = hexp2(s[qi][kc][2] - m[qi]);
        float p3 = hexp2(s[qi][kc][3] - m[qi]);
        psum += (p0 + p1) + (p2 + p3);
        uint2 pk;
        pk.x = cvt_pk_bf16(p0, p1);
        pk.y = cvt_pk_bf16(p2, p3);
        *reinterpret_cast<uint2*>(Pw + ((rowbase + kc * 32 + lg * 8) ^ swz)) = pk;
      }
      lsum[qi] += psum;
    }
    asm volatile("s_waitcnt lgkmcnt(0)" ::: "memory");
    // ---- PV (swapped): o[qi][d] += mfma(Vfrag, Pfrag)
    __builtin_amdgcn_s_setprio(1);
    {
      bf16x8 pa0 = *reinterpret_cast<const bf16x8*>(Pw + (((0 * 16 + lr) * 128 + lg * 16) ^ swz));
      bf16x8 pa1 = *reinterpret_cast<const bf16x8*>(Pw + (((1 * 16 + lr) * 128 + lg * 16) ^ swz));
      o[0][0] = MFMA16(vA0, pa0, o[0][0], 0, 0, 0);
      o[0][1] = MFMA16(vA1, pa0, o[0][1], 0, 0, 0);
      o[0][2] = MFMA16(vA2, pa0, o[0][2], 0, 0, 0);
      o[0][3] = MFMA16(vA3, pa0, o[0][3], 0, 0, 0);
      o[1][0] = MFMA16(vA0, pa1, o[1][0], 0, 0, 0);
      o[1][1] = MFMA16(vA1, pa1, o[1][1], 0, 0, 0);
      o[1][2] = MFMA16(vA2, pa1, o[1][2], 0, 0, 0);
      o[1][3] = MFMA16(vA3, pa1, o[1][3], 0, 0, 0);
      pa0 = *reinterpret_cast<const bf16x8*>(Pw + (((0 * 16 + lr) * 128 + 64 + lg * 16) ^ swz));
      pa1 = *reinterpret_cast<const bf16x8*>(Pw + (((1 * 16 + lr) * 128 + 64 + lg * 16) ^ swz));
      o[0][0] = MFMA16(vB0, pa0, o[0][0], 0, 0, 0);
      o[0][1] = MFMA16(vB1, pa0, o[0][1], 0, 0, 0);
      o[0][2] = MFMA16(vB2, pa0, o[0][2], 0, 0, 0);
      o[0][3] = MFMA16(vB3, pa0, o[0][3], 0, 0, 0);
      o[1][0] = MFMA16(vB0, pa1, o[1][0], 0, 0, 0);
      o[1][1] = MFMA16(vB1, pa1, o[1][1], 0, 0, 0);
      o[1][2] = MFMA16(vB2, pa1, o[1][2], 0, 0, 0);
      o[1][3] = MFMA16(vB3, pa1, o[1][3], 0, 0, 0);
    }
    __builtin_amdgcn_s_setprio(0);
    if (tt < 31) LOAD_V(j0 + 64);            // prefetch next V tile
  }

  // ---- epilogue: reduce l across the 4 lanes of each row, normalize, write [B,T,C] bf16
  int b = bh >> 4, h = bh & 15;
  for (int qi = 0; qi < 2; ++qi) {
    float ls = lsum[qi];
    ls += __shfl_xor(ls, 16);
    ls += __shfl_xor(ls, 32);
    float inv = 1.0f / ls;
    size_t rowoff = ((size_t)b * 2048 + q0 + qi * 16 + lr) * 1024 + h * 64;
    for (int d = 0; d < 4; ++d) {
      uint2 pk;
      pk.x = cvt_pk_bf16(o[qi][d][0] * inv, o[qi][d][1] * inv);
      pk.y = cvt_pk_bf16(o[qi][d][2] * inv, o[qi][d][3] * inv);
      *reinterpret_cast<uint2*>(&ab[rowoff + d * 16 + lg * 4]) = pk;
    }
  }
#undef LOAD_K
#undef LOAD_V
}

// ---------------- launcher ----------------
extern "C" void kernel_launch(void* const* d_in, const int* in_sizes, int n_in,
                              void* d_out, int out_size, void* d_ws, size_t ws_size,
                              hipStream_t stream) {
  const float* x  = (const float*)d_in[0];
  const float* Wq = (const float*)d_in[1];
  const float* bq = (const float*)d_in[2];
  const float* Wk = (const float*)d_in[3];
  const float* bk = (const float*)d_in[4];
  const float* Wv = (const float*)d_in[5];
  const float* bv = (const float*)d_in[6];
  const float* Wo = (const float*)d_in[7];
  const float* bo = (const float*)d_in[8];

  u16* ws  = (u16*)d_ws;
  u16* xb  = ws;                 // 4096*1024 bf16 (reused for attention output)
  u16* wqb = ws + 4194304;
  u16* wkb = ws + 5242880;
  u16* wvb = ws + 6291456;
  u16* wob = ws + 7340032;
  u16* qbf = ws + 8388608;
  u16* kbf = ws + 12582912;
  u16* vbf = ws + 16777216;
  u16* ab  = xb;

  // fp32 -> bf16 (x + all four weights, one launch)
  f2b5_kernel<<<8192, 256, 0, stream>>>(x, Wq, Wk, Wv, Wo, xb, wqb, wkb, wvb, wob);

  // fused QKV projection (Q scaled 1/8*log2e, V transposed)
  gemm_qkv<<<dim3(32, 24), 256, 0, stream>>>(xb, wqb, wkb, wvb, bq, bk, bv, qbf, kbf, vbf);

  attn_kernel<<<dim3(16, 32), 256, 0, stream>>>(qbf, kbf, vbf, ab);

  gemm_out<<<dim3(32, 8), 256, 0, stream>>>(ab, wob, bo, (float*)d_out);
}

// Round 20
// 134.989 us; speedup vs baseline: 1.4283x; 1.4283x over previous
//
#include <hip/hip_runtime.h>
#include <stdint.h>

// LocalAttention: x[2,2048,1024] -> QKV proj -> anti-local attention (keep |i-j|>16) -> out proj.
// Round 20: revert to r18 (proven best 134.9us; r19's direct-global K/V was request/latency-bound,
// 2x regression) + XCD remap for gemm_out (bm-grouped: 4 A-panels + W = 3MB/XCD, L2-resident).

typedef unsigned short u16;
typedef short bf16x8 __attribute__((ext_vector_type(8)));
typedef float f32x4 __attribute__((ext_vector_type(4)));

#define MFMA16 __builtin_amdgcn_mfma_f32_16x16x32_bf16

__device__ __forceinline__ u16 f2bf(float f) {
  union { float f; uint32_t u; } v; v.f = f;
  return (u16)((v.u + 0x7fffu + ((v.u >> 16) & 1u)) >> 16);
}

__device__ __forceinline__ uint32_t cvt_pk_bf16(float lo, float hi) {
  uint32_t d;
  asm("v_cvt_pk_bf16_f32 %0, %1, %2" : "=v"(d) : "v"(lo), "v"(hi));
  return d;
}

// raw hardware exp2 (v_exp_f32 IS exp2 on gfx950; no libm guard code)
__device__ __forceinline__ float hexp2(float x) {
  float r;
  asm("v_exp_f32 %0, %1" : "=v"(r) : "v"(x));
  return r;
}

// ---------------- fp32 -> bf16 conversion (x + 4 weights, ONE launch) ----------------
__global__ void f2b5_kernel(const float* __restrict__ x,
                            const float* __restrict__ a, const float* __restrict__ b,
                            const float* __restrict__ c, const float* __restrict__ d,
                            u16* __restrict__ ox, u16* __restrict__ oa, u16* __restrict__ ob,
                            u16* __restrict__ oc, u16* __restrict__ od) {
  int bid = blockIdx.x;
  const float* src; u16* dst; int base;
  if (bid < 4096)      { src = x; dst = ox; base = 0; }
  else if (bid < 5120) { src = a; dst = oa; base = 4096; }
  else if (bid < 6144) { src = b; dst = ob; base = 5120; }
  else if (bid < 7168) { src = c; dst = oc; base = 6144; }
  else                 { src = d; dst = od; base = 7168; }
  int i = (bid - base) * 256 + threadIdx.x;
  float4 v = reinterpret_cast<const float4*>(src)[i];
  ushort4 o;
  o.x = f2bf(v.x); o.y = f2bf(v.y); o.z = f2bf(v.z); o.w = f2bf(v.w);
  reinterpret_cast<ushort4*>(dst)[i] = o;
}

// ---------------- shared GEMM core (padded LDS, reg-staged, NAMED registers) ----------------
#define GEMM_LOAD(REGA, REGB, A_, B_, KOFF)                                                        \
  do {                                                                                             \
    REGA##0 = *reinterpret_cast<const uint4*>(A_ + (size_t)(gm_base +  0) * 1024 + (KOFF) + sslot * 8); \
    REGA##1 = *reinterpret_cast<const uint4*>(A_ + (size_t)(gm_base + 32) * 1024 + (KOFF) + sslot * 8); \
    REGA##2 = *reinterpret_cast<const uint4*>(A_ + (size_t)(gm_base + 64) * 1024 + (KOFF) + sslot * 8); \
    REGA##3 = *reinterpret_cast<const uint4*>(A_ + (size_t)(gm_base + 96) * 1024 + (KOFF) + sslot * 8); \
    REGB##0 = *reinterpret_cast<const uint4*>(B_ + (size_t)(gn_base +  0) * 1024 + (KOFF) + sslot * 8); \
    REGB##1 = *reinterpret_cast<const uint4*>(B_ + (size_t)(gn_base + 32) * 1024 + (KOFF) + sslot * 8); \
    REGB##2 = *reinterpret_cast<const uint4*>(B_ + (size_t)(gn_base + 64) * 1024 + (KOFF) + sslot * 8); \
    REGB##3 = *reinterpret_cast<const uint4*>(B_ + (size_t)(gn_base + 96) * 1024 + (KOFF) + sslot * 8); \
  } while (0)

#define GEMM_PUBLISH()                                                                             \
  do {                                                                                             \
    *reinterpret_cast<uint4*>((char*)As + (srow +  0) * 144 + sslot * 16) = ar0;                   \
    *reinterpret_cast<uint4*>((char*)As + (srow + 32) * 144 + sslot * 16) = ar1;                   \
    *reinterpret_cast<uint4*>((char*)As + (srow + 64) * 144 + sslot * 16) = ar2;                   \
    *reinterpret_cast<uint4*>((char*)As + (srow + 96) * 144 + sslot * 16) = ar3;                   \
    *reinterpret_cast<uint4*>((char*)Bs + (srow +  0) * 144 + sslot * 16) = br0;                   \
    *reinterpret_cast<uint4*>((char*)Bs + (srow + 32) * 144 + sslot * 16) = br1;                   \
    *reinterpret_cast<uint4*>((char*)Bs + (srow + 64) * 144 + sslot * 16) = br2;                   \
    *reinterpret_cast<uint4*>((char*)Bs + (srow + 96) * 144 + sslot * 16) = br3;                   \
  } while (0)

#define GEMM_CORE(A_, B_, bm0_, bn0_)                                                              \
  constexpr int KP = 72;                                                                           \
  __shared__ __align__(16) u16 As[128 * KP];                                                       \
  __shared__ __align__(16) u16 Bs[128 * KP];                                                       \
  const int t = threadIdx.x;                                                                       \
  const int lane = t & 63;                                                                         \
  const int wv = t >> 6;                                                                           \
  const int wm = (wv >> 1) * 64;                                                                   \
  const int wn = (wv & 1) * 64;                                                                    \
  const int lg = lane >> 4;                                                                        \
  const int lr = lane & 15;                                                                        \
  const int srow = t >> 3;                                                                         \
  const int sslot = t & 7;                                                                         \
  const int gm_base = bm0_ + srow;                                                                 \
  const int gn_base = bn0_ + srow;                                                                 \
  uint4 ar0, ar1, ar2, ar3, br0, br1, br2, br3;                                                    \
  f32x4 acc[4][4];                                                                                 \
  for (int i = 0; i < 4; ++i)                                                                      \
    for (int j = 0; j < 4; ++j) acc[i][j] = (f32x4)0.0f;                                           \
  GEMM_LOAD(ar, br, A_, B_, 0);                                                                    \
  for (int k0 = 0; k0 < 1024; k0 += 64) {                                                          \
    GEMM_PUBLISH();                                                                                \
    __syncthreads();                                                                               \
    if (k0 + 64 < 1024) GEMM_LOAD(ar, br, A_, B_, k0 + 64);                                        \
    for (int kk = 0; kk < 2; ++kk) {                                                               \
      bf16x8 af[4], bfr[4];                                                                        \
      for (int i = 0; i < 4; ++i)                                                                  \
        af[i] = *reinterpret_cast<const bf16x8*>(&As[(wm + i * 16 + lr) * KP + kk * 32 + lg * 8]); \
      for (int j = 0; j < 4; ++j)                                                                  \
        bfr[j] = *reinterpret_cast<const bf16x8*>(&Bs[(wn + j * 16 + lr) * KP + kk * 32 + lg * 8]);\
      for (int i = 0; i < 4; ++i)                                                                  \
        for (int j = 0; j < 4; ++j)                                                                \
          acc[i][j] = MFMA16(af[i], bfr[j], acc[i][j], 0, 0, 0);                                   \
    }                                                                                              \
    __syncthreads();                                                                               \
  }

// ---------------- fused QKV GEMM ----------------
__global__ __launch_bounds__(256) void gemm_qkv(
    const u16* __restrict__ A,
    const u16* __restrict__ Wqb, const u16* __restrict__ Wkb, const u16* __restrict__ Wvb,
    const float* __restrict__ bqp, const float* __restrict__ bkp, const float* __restrict__ bvp,
    u16* __restrict__ qo, u16* __restrict__ ko, u16* __restrict__ vo)
{
  const int bid = blockIdx.x + gridDim.x * blockIdx.y;
  const int sid = (bid & 7) * 96 + (bid >> 3);
  const int bm0 = (sid / 24) * 128;
  const int jy = sid % 24;
  const int sel = jy >> 3;
  const int bn0 = (jy & 7) * 128;

  const u16* Bw = (sel == 0) ? Wqb : (sel == 1) ? Wkb : Wvb;
  const float* bias = (sel == 0) ? bqp : (sel == 1) ? bkp : bvp;
  // Q scale folds softmax 1/8 AND log2(e) (exp2-domain softmax downstream)
  const float scale = (sel == 0) ? 0.125f * 1.44269504f : 1.0f;

  GEMM_CORE(A, Bw, bm0, bn0)

  for (int j = 0; j < 4; ++j) {
    int gn = bn0 + wn + j * 16 + lr;
    float bv = bias[gn];
    for (int i = 0; i < 4; ++i) {
      for (int r = 0; r < 4; ++r) {
        int gm = bm0 + wm + i * 16 + lg * 4 + r;
        float val = (acc[i][j][r] + bv) * scale;
        int b = gm >> 11, tt = gm & 2047;
        int h = gn >> 6,  d = gn & 63;
        u16 o = f2bf(val);
        if (sel == 0)
          qo[((size_t)(b * 16 + h) * 2048 + tt) * 64 + d] = o;
        else if (sel == 1)
          ko[((size_t)(b * 16 + h) * 2048 + tt) * 64 + d] = o;
        else
          vo[((size_t)(b * 16 + h) * 64 + d) * 2048 + tt] = o;
      }
    }
  }
}

// ---------------- out-proj GEMM: C[M,N] fp32 = A @ W^T + bias (XCD-remapped) ----------------
__global__ __launch_bounds__(256) void gemm_out(
    const u16* __restrict__ A, const u16* __restrict__ Bw,
    const float* __restrict__ bias, float* __restrict__ outp)
{
  // 256 blocks = 8 XCDs x 32; XCD k serves bm 4k..4k+3 (4 A-panels + full W ~= 3MB, L2-fits)
  const int bid = blockIdx.x + gridDim.x * blockIdx.y;
  const int sid = (bid & 7) * 32 + (bid >> 3);
  const int bm0 = (sid >> 3) * 128;
  const int bn0 = (sid & 7) * 128;

  GEMM_CORE(A, Bw, bm0, bn0)

  for (int j = 0; j < 4; ++j) {
    int gn = bn0 + wn + j * 16 + lr;
    float bv = bias[gn];
    for (int i = 0; i < 4; ++i)
      for (int r = 0; r < 4; ++r) {
        int gm = bm0 + wm + i * 16 + lg * 4 + r;
        outp[(size_t)gm * 1024 + gn] = acc[i][j][r] + bv;
      }
  }
}

// ---------------- attention (r18 proven: padded K/V LDS dbuf, setprio, hw-exp2) ----------------
__global__ __launch_bounds__(256, 2) void attn_kernel(
    const u16* __restrict__ qb, const u16* __restrict__ kb,
    const u16* __restrict__ vtb, u16* __restrict__ ab)
{
  constexpr int KP = 72;
  __shared__ __align__(16) u16 Kb[2][64 * KP];
  __shared__ __align__(16) u16 Vb[2][64 * KP];
  __shared__ __align__(16) u16 Pl[4][32 * 64];

  const int bid = blockIdx.x + gridDim.x * blockIdx.y;
  const int sid = (bid & 7) * 64 + (bid >> 3);
  const int bx = sid & 15;
  const int bh = sid >> 4;                   // b*16+h

  const int t = threadIdx.x;
  const int lane = t & 63;
  const int wv = t >> 6;
  const int lg = lane >> 4, lr = lane & 15;
  const int q0 = bx * 128 + wv * 32;

  const u16* Qp = qb + (size_t)bh * 2048 * 64;
  const u16* Kp = kb + (size_t)bh * 2048 * 64;
  const u16* Vt = vtb + (size_t)bh * 64 * 2048;
  char* Pw = (char*)&Pl[wv][0];
  const int swz = (lr & 7) << 4;             // P-tile XOR swizzle (proven)

  const int sl = lane & 7;
  const int r0 = wv * 16 + (lane >> 3);
  const int sdst0 = r0 * (KP * 2) + sl * 16;

  uint4 krA, krB, vrA, vrB;

#define ISSUE_LOADS(J0N)                                                                 \
  do {                                                                                   \
    krA = *reinterpret_cast<const uint4*>(Kp + (size_t)((J0N) + r0) * 64 + sl * 8);      \
    krB = *reinterpret_cast<const uint4*>(Kp + (size_t)((J0N) + r0 + 8) * 64 + sl * 8);  \
    vrA = *reinterpret_cast<const uint4*>(Vt + (size_t)r0 * 2048 + (J0N) + sl * 8);      \
    vrB = *reinterpret_cast<const uint4*>(Vt + (size_t)(r0 + 8) * 2048 + (J0N) + sl * 8);\
  } while (0)

#define WRITE_LDS(BUF)                                                                   \
  do {                                                                                   \
    *reinterpret_cast<uint4*>((char*)&Kb[BUF][0] + sdst0)                = krA;          \
    *reinterpret_cast<uint4*>((char*)&Kb[BUF][0] + sdst0 + 8 * KP * 2)   = krB;          \
    *reinterpret_cast<uint4*>((char*)&Vb[BUF][0] + sdst0)                = vrA;          \
    *reinterpret_cast<uint4*>((char*)&Vb[BUF][0] + sdst0 + 8 * KP * 2)   = vrB;          \
  } while (0)

  bf16x8 qf[2][2];
  for (int qi = 0; qi < 2; ++qi)
    for (int h = 0; h < 2; ++h)
      qf[qi][h] = *reinterpret_cast<const bf16x8*>(&Qp[(size_t)(q0 + qi * 16 + lr) * 64 + h * 32 + lg * 8]);

  f32x4 o[2][4];
  for (int qi = 0; qi < 2; ++qi)
    for (int d = 0; d < 4; ++d) o[qi][d] = (f32x4)0.0f;
  float m[2] = {-1e30f, -1e30f};             // running max (log2 domain)
  float lsum[2] = {0.0f, 0.0f};              // per-lane partial sums (reduced in epilogue)

  ISSUE_LOADS(0);
  WRITE_LDS(0);
  __syncthreads();
  int cur = 0;

  for (int tt = 0; tt < 32; ++tt) {
    if (tt < 31) ISSUE_LOADS((tt + 1) * 64);
    const int j0 = tt * 64;

    // ---- QK^T (swapped): s[qi][kc] -> lane: q=q0+qi*16+lr, key=j0+kc*16+lg*4+r
    f32x4 s[2][4];
    __builtin_amdgcn_s_setprio(1);
    for (int kc = 0; kc < 4; ++kc) {
      bf16x8 kf0 = *reinterpret_cast<const bf16x8*>(&Kb[cur][(kc * 16 + lr) * KP + lg * 8]);
      bf16x8 kf1 = *reinterpret_cast<const bf16x8*>(&Kb[cur][(kc * 16 + lr) * KP + 32 + lg * 8]);
      for (int qi = 0; qi < 2; ++qi) {
        f32x4 z = (f32x4)0.0f;
        z = MFMA16(kf0, qf[qi][0], z, 0, 0, 0);
        z = MFMA16(kf1, qf[qi][1], z, 0, 0, 0);
        s[qi][kc] = z;
      }
    }
    __builtin_amdgcn_s_setprio(0);
    // ---- mask band |i-j| <= 16
    if (j0 + 63 >= q0 - 16 && j0 <= q0 + 47) {
      for (int qi = 0; qi < 2; ++qi)
        for (int kc = 0; kc < 4; ++kc)
          for (int r = 0; r < 4; ++r) {
            int i = q0 + qi * 16 + lr;
            int j = j0 + kc * 16 + lg * 4 + r;
            int dd = i - j; if (dd < 0) dd = -dd;
            if (dd <= 16) s[qi][kc][r] = -1e38f;
          }
    }
    // ---- tile row-max
    float pm[2];
    for (int qi = 0; qi < 2; ++qi) {
      f32x4 t4 = __builtin_elementwise_max(__builtin_elementwise_max(s[qi][0], s[qi][1]),
                                           __builtin_elementwise_max(s[qi][2], s[qi][3]));
      float x = fmaxf(fmaxf(t4[0], t4[1]), fmaxf(t4[2], t4[3]));
      x = fmaxf(x, __shfl_xor(x, 16));
      x = fmaxf(x, __shfl_xor(x, 32));
      pm[qi] = x;
    }
    // ---- defer-max rescale (log2 units; exp2(11.54) == exp(8) bound)
    bool need = (pm[0] > m[0] + 11.54f) || (pm[1] > m[1] + 11.54f);
    if (__any((int)need)) {
      for (int qi = 0; qi < 2; ++qi) {
        float mn = fmaxf(m[qi], pm[qi]);
        float a = hexp2(m[qi] - mn);
        m[qi] = mn;
        lsum[qi] *= a;
        for (int d = 0; d < 4; ++d) o[qi][d] *= a;
      }
    }
    // ---- p = exp2(s-m), pack to LDS; per-lane partial sum only (no shuffles)
    for (int qi = 0; qi < 2; ++qi) {
      int rowbase = (qi * 16 + lr) * 128;
      float psum = 0.0f;
      for (int kc = 0; kc < 4; ++kc) {
        float p0 = hexp2(s[qi][kc][0] - m[qi]);
        float p1 = hexp2(s[qi][kc][1] - m[qi]);
        float p2 = hexp2(s[qi][kc][2] - m[qi]);
        float p3 = hexp2(s[qi][kc][3] - m[qi]);
        psum += (p0 + p1) + (p2 + p3);
        uint2 pk;
        pk.x = cvt_pk_bf16(p0, p1);
        pk.y = cvt_pk_bf16(p2, p3);
        *reinterpret_cast<uint2*>(Pw + ((rowbase + kc * 32 + lg * 8) ^ swz)) = pk;
      }
      lsum[qi] += psum;
    }
    asm volatile("s_waitcnt lgkmcnt(0)" ::: "memory");
    // ---- PV (swapped): o[qi][d] += mfma(Vfrag, Pfrag)
    __builtin_amdgcn_s_setprio(1);
    for (int kh = 0; kh < 2; ++kh) {
      bf16x8 pa[2];
      for (int qi = 0; qi < 2; ++qi)
        pa[qi] = *reinterpret_cast<const bf16x8*>(
            Pw + (((qi * 16 + lr) * 128 + kh * 64 + lg * 16) ^ swz));
      for (int d = 0; d < 4; ++d) {
        bf16x8 vf = *reinterpret_cast<const bf16x8*>(
            &Vb[cur][(d * 16 + lr) * KP + kh * 32 + lg * 8]);
        for (int qi = 0; qi < 2; ++qi)
          o[qi][d] = MFMA16(vf, pa[qi], o[qi][d], 0, 0, 0);
      }
    }
    __builtin_amdgcn_s_setprio(0);
    if (tt < 31) WRITE_LDS(cur ^ 1);
    __syncthreads();
    cur ^= 1;
  }

  // ---- epilogue: reduce l across the 4 lanes of each row, normalize, write [B,T,C] bf16
  int b = bh >> 4, h = bh & 15;
  for (int qi = 0; qi < 2; ++qi) {
    float ls = lsum[qi];
    ls += __shfl_xor(ls, 16);
    ls += __shfl_xor(ls, 32);
    float inv = 1.0f / ls;
    size_t rowoff = ((size_t)b * 2048 + q0 + qi * 16 + lr) * 1024 + h * 64;
    for (int d = 0; d < 4; ++d) {
      uint2 pk;
      pk.x = cvt_pk_bf16(o[qi][d][0] * inv, o[qi][d][1] * inv);
      pk.y = cvt_pk_bf16(o[qi][d][2] * inv, o[qi][d][3] * inv);
      *reinterpret_cast<uint2*>(&ab[rowoff + d * 16 + lg * 4]) = pk;
    }
  }
#undef ISSUE_LOADS
#undef WRITE_LDS
}

// ---------------- launcher ----------------
extern "C" void kernel_launch(void* const* d_in, const int* in_sizes, int n_in,
                              void* d_out, int out_size, void* d_ws, size_t ws_size,
                              hipStream_t stream) {
  const float* x  = (const float*)d_in[0];
  const float* Wq = (const float*)d_in[1];
  const float* bq = (const float*)d_in[2];
  const float* Wk = (const float*)d_in[3];
  const float* bk = (const float*)d_in[4];
  const float* Wv = (const float*)d_in[5];
  const float* bv = (const float*)d_in[6];
  const float* Wo = (const float*)d_in[7];
  const float* bo = (const float*)d_in[8];

  u16* ws  = (u16*)d_ws;
  u16* xb  = ws;                 // 4096*1024 bf16 (reused for attention output)
  u16* wqb = ws + 4194304;
  u16* wkb = ws + 5242880;
  u16* wvb = ws + 6291456;
  u16* wob = ws + 7340032;
  u16* qbf = ws + 8388608;
  u16* kbf = ws + 12582912;
  u16* vbf = ws + 16777216;
  u16* ab  = xb;

  // fp32 -> bf16 (x + all four weights, one launch)
  f2b5_kernel<<<8192, 256, 0, stream>>>(x, Wq, Wk, Wv, Wo, xb, wqb, wkb, wvb, wob);

  // fused QKV projection (Q scaled 1/8*log2e, V transposed)
  gemm_qkv<<<dim3(32, 24), 256, 0, stream>>>(xb, wqb, wkb, wvb, bq, bk, bv, qbf, kbf, vbf);

  attn_kernel<<<dim3(16, 32), 256, 0, stream>>>(qbf, kbf, vbf, ab);

  gemm_out<<<dim3(32, 8), 256, 0, stream>>>(ab, wob, bo, (float*)d_out);
}